// Round 1
// baseline (19438.925 us; speedup 1.0000x reference)
//
#include <hip/hip_runtime.h>

#define NTHREADS 256

__device__ __forceinline__ float gelu_f(float x) {
    return 0.5f * x * (1.0f + erff(x * 0.70710678118654752440f));
}

__global__ __launch_bounds__(NTHREADS, 2)
void gno_fused(const float* __restrict__ rndata,   // [16000,64]
               const float* __restrict__ qpos,     // [100000,3]
               const float* __restrict__ latpos,   // [16000,3]
               const int*   __restrict__ edge_dst, // [E]
               const int*   __restrict__ edge_src, // [E]
               const float* __restrict__ kW0, const float* __restrict__ kb0,
               const float* __restrict__ kW1, const float* __restrict__ kb1,
               const float* __restrict__ kW2, const float* __restrict__ kb2,
               const float* __restrict__ pW1, const float* __restrict__ pb1,
               const float* __restrict__ pW2, const float* __restrict__ pb2,
               float* __restrict__ out)            // [100000,4]
{
    __shared__ float sW0[6 * 64];
    __shared__ float sW1[64 * 64];
    __shared__ float sW2[64 * 64];
    __shared__ float sb0[64], sb1[64], sb2[64];
    __shared__ float spb1[256];
    __shared__ float spW2[256 * 4];
    __shared__ float spb2[4];
    __shared__ float sdec[16 * 68];   // 16 queries x 64 channels, pad 68 to break banks

    const int tid = threadIdx.x;

    for (int i = tid; i < 6 * 64; i += NTHREADS) sW0[i] = kW0[i];
    for (int i = tid; i < 64 * 64; i += NTHREADS) { sW1[i] = kW1[i]; sW2[i] = kW2[i]; }
    if (tid < 64) { sb0[tid] = kb0[tid]; sb1[tid] = kb1[tid]; sb2[tid] = kb2[tid]; }
    spb1[tid] = pb1[tid];                      // NTHREADS == 256
    for (int i = tid; i < 256 * 4; i += NTHREADS) spW2[i] = pW2[i];
    if (tid < 4) spb2[tid] = pb2[tid];
    __syncthreads();

    const int e   = blockIdx.x * NTHREADS + tid;   // E = 1,600,000 = 6250*256 exactly
    const int src = edge_src[e];
    const int dst = edge_dst[e];

    const float efv[6] = { latpos[src * 3 + 0], latpos[src * 3 + 1], latpos[src * 3 + 2],
                           qpos  [dst * 3 + 0], qpos  [dst * 3 + 1], qpos  [dst * 3 + 2] };

    float h[64], a[64];

    // ---- layer 0: [6] -> [64], GELU ----
    #pragma unroll
    for (int i = 0; i < 64; ++i) a[i] = sb0[i];
    #pragma unroll
    for (int j = 0; j < 6; ++j) {
        const float hj = efv[j];
        #pragma unroll
        for (int i4 = 0; i4 < 16; ++i4) {
            const float4 w = *(const float4*)&sW0[j * 64 + i4 * 4];
            a[i4 * 4 + 0] += hj * w.x; a[i4 * 4 + 1] += hj * w.y;
            a[i4 * 4 + 2] += hj * w.z; a[i4 * 4 + 3] += hj * w.w;
        }
    }
    #pragma unroll
    for (int i = 0; i < 64; ++i) h[i] = gelu_f(a[i]);

    // ---- layer 1: [64] -> [64], GELU ----
    #pragma unroll
    for (int i = 0; i < 64; ++i) a[i] = sb1[i];
    #pragma unroll
    for (int j = 0; j < 64; ++j) {
        const float hj = h[j];
        #pragma unroll
        for (int i4 = 0; i4 < 16; ++i4) {
            const float4 w = *(const float4*)&sW1[j * 64 + i4 * 4];
            a[i4 * 4 + 0] += hj * w.x; a[i4 * 4 + 1] += hj * w.y;
            a[i4 * 4 + 2] += hj * w.z; a[i4 * 4 + 3] += hj * w.w;
        }
    }
    #pragma unroll
    for (int i = 0; i < 64; ++i) a[i] = gelu_f(a[i]);

    // ---- layer 2: [64] -> [64], no activation (kern -> h) ----
    #pragma unroll
    for (int i = 0; i < 64; ++i) h[i] = sb2[i];
    #pragma unroll
    for (int j = 0; j < 64; ++j) {
        const float hj = a[j];
        #pragma unroll
        for (int i4 = 0; i4 < 16; ++i4) {
            const float4 w = *(const float4*)&sW2[j * 64 + i4 * 4];
            h[i4 * 4 + 0] += hj * w.x; h[i4 * 4 + 1] += hj * w.y;
            h[i4 * 4 + 2] += hj * w.z; h[i4 * 4 + 3] += hj * w.w;
        }
    }

    // ---- rep = kern * rndata[src]; mean over the 16 edges of this query ----
    const float* rn = rndata + (size_t)src * 64;
    const int sub = tid & 15;   // lane within the query's 16-edge group
    const int lq  = tid >> 4;   // local query index 0..15
    float dec0 = 0.f, dec1 = 0.f, dec2 = 0.f, dec3 = 0.f;
    #pragma unroll
    for (int i4 = 0; i4 < 16; ++i4) {
        const float4 r4 = *(const float4*)&rn[i4 * 4];
        float v0 = h[i4 * 4 + 0] * r4.x, v1 = h[i4 * 4 + 1] * r4.y;
        float v2 = h[i4 * 4 + 2] * r4.z, v3 = h[i4 * 4 + 3] * r4.w;
        #pragma unroll
        for (int m = 1; m < 16; m <<= 1) {
            v0 += __shfl_xor(v0, m, 16);
            v1 += __shfl_xor(v1, m, 16);
            v2 += __shfl_xor(v2, m, 16);
            v3 += __shfl_xor(v3, m, 16);
        }
        if (sub == i4) { dec0 = v0 * 0.0625f; dec1 = v1 * 0.0625f;
                         dec2 = v2 * 0.0625f; dec3 = v3 * 0.0625f; }
    }
    *(float4*)&sdec[lq * 68 + sub * 4] = make_float4(dec0, dec1, dec2, dec3);
    __syncthreads();

    // ---- projection: gelu(dec @ pW1 + pb1) @ pW2 + pb2, 16 lanes per query ----
    float o0 = 0.f, o1 = 0.f, o2 = 0.f, o3 = 0.f;
    #pragma unroll
    for (int b = 0; b < 4; ++b) {
        const int u0 = sub * 4 + b * 64;          // this lane's 4 hidden units
        float s0 = spb1[u0 + 0], s1 = spb1[u0 + 1], s2 = spb1[u0 + 2], s3 = spb1[u0 + 3];
        for (int j4 = 0; j4 < 16; ++j4) {
            const float4 d4 = *(const float4*)&sdec[lq * 68 + j4 * 4];
            const float4 w0 = *(const float4*)&pW1[(j4 * 4 + 0) * 256 + u0];
            const float4 w1 = *(const float4*)&pW1[(j4 * 4 + 1) * 256 + u0];
            const float4 w2 = *(const float4*)&pW1[(j4 * 4 + 2) * 256 + u0];
            const float4 w3 = *(const float4*)&pW1[(j4 * 4 + 3) * 256 + u0];
            s0 += d4.x * w0.x + d4.y * w1.x + d4.z * w2.x + d4.w * w3.x;
            s1 += d4.x * w0.y + d4.y * w1.y + d4.z * w2.y + d4.w * w3.y;
            s2 += d4.x * w0.z + d4.y * w1.z + d4.z * w2.z + d4.w * w3.z;
            s3 += d4.x * w0.w + d4.y * w1.w + d4.z * w2.w + d4.w * w3.w;
        }
        const float g0 = gelu_f(s0), g1 = gelu_f(s1), g2 = gelu_f(s2), g3 = gelu_f(s3);
        const float4 w20 = *(const float4*)&spW2[(u0 + 0) * 4];
        const float4 w21 = *(const float4*)&spW2[(u0 + 1) * 4];
        const float4 w22 = *(const float4*)&spW2[(u0 + 2) * 4];
        const float4 w23 = *(const float4*)&spW2[(u0 + 3) * 4];
        o0 += g0 * w20.x + g1 * w21.x + g2 * w22.x + g3 * w23.x;
        o1 += g0 * w20.y + g1 * w21.y + g2 * w22.y + g3 * w23.y;
        o2 += g0 * w20.z + g1 * w21.z + g2 * w22.z + g3 * w23.z;
        o3 += g0 * w20.w + g1 * w21.w + g2 * w22.w + g3 * w23.w;
    }
    #pragma unroll
    for (int m = 1; m < 16; m <<= 1) {
        o0 += __shfl_xor(o0, m, 16);
        o1 += __shfl_xor(o1, m, 16);
        o2 += __shfl_xor(o2, m, 16);
        o3 += __shfl_xor(o3, m, 16);
    }
    if (sub == 0) {
        const int q = blockIdx.x * 16 + lq;
        *(float4*)&out[(size_t)q * 4] =
            make_float4(o0 + spb2[0], o1 + spb2[1], o2 + spb2[2], o3 + spb2[3]);
    }
}

extern "C" void kernel_launch(void* const* d_in, const int* in_sizes, int n_in,
                              void* d_out, int out_size, void* d_ws, size_t ws_size,
                              hipStream_t stream)
{
    const float* rndata = (const float*)d_in[0];
    const float* qpos   = (const float*)d_in[1];
    const float* latpos = (const float*)d_in[3];
    const int*   edge   = (const int*)d_in[5];
    const float* kW0 = (const float*)d_in[6];
    const float* kb0 = (const float*)d_in[7];
    const float* kW1 = (const float*)d_in[8];
    const float* kb1 = (const float*)d_in[9];
    const float* kW2 = (const float*)d_in[10];
    const float* kb2 = (const float*)d_in[11];
    const float* pW1 = (const float*)d_in[12];
    const float* pb1 = (const float*)d_in[13];
    const float* pW2 = (const float*)d_in[14];
    const float* pb2 = (const float*)d_in[15];
    float* out = (float*)d_out;

    const int E = in_sizes[5] / 2;          // 1,600,000
    const int nblocks = E / NTHREADS;       // 6250, exact

    gno_fused<<<nblocks, NTHREADS, 0, stream>>>(
        rndata, qpos, latpos, edge, edge + E,
        kW0, kb0, kW1, kb1, kW2, kb2, pW1, pb1, pW2, pb2, out);
}